// Round 6
// baseline (756.632 us; speedup 1.0000x reference)
//
#include <hip/hip_runtime.h>

// DiffusionPropagate: out[b,i] = 1 - prod_j (1 - adj[j,i] * p[b,j]), 3 iters.
// B=4, N=4096. R5 post-mortem: occupancy/ILP doubling gained only 8% ->
// latency theory dead; our 6 dispatches never appear in top-5 (each <40us)
// while dur_us=160 -> suspect inter-dispatch overhead and/or ~40us stage1.
// R6: ONE persistent kernel (1024 blocks, device-scope spin barriers in ws,
// counters zeroed by captured hipMemsetAsync). Same per-iter work as R5.
// Goal: kill graph-node gaps AND surface our counters in top-5.

#define N 4096
#define B 4
#define CHUNKS 128
#define JC (N / CHUNKS)          // 32 j per chunk
#define T1 128                   // threads per block (2 waves)
#define IPANELS 8                // N / (T1*4) i-panels
#define NBLK (IPANELS * CHUNKS)  // 1024 blocks = 4 blocks/CU (co-resident)

__device__ __forceinline__ void grid_barrier(unsigned* ctr, unsigned target) {
    __syncthreads();
    if (threadIdx.x == 0) {
        __threadfence();                       // release: flush partial writes
        atomicAdd(ctr, 1u);
        while (__hip_atomic_load(ctr, __ATOMIC_RELAXED,
                                 __HIP_MEMORY_SCOPE_AGENT) < target) {
            __builtin_amdgcn_s_sleep(8);
        }
    }
    __syncthreads();
    __threadfence();                           // acquire: invalidate stale lines
}

__global__ __launch_bounds__(T1) void diffusion_fused(
    const float* __restrict__ adj,      // [N][N]
    const float* __restrict__ preds,    // [B][N]
    float* __restrict__ p0,             // [B][N] scratch
    float* __restrict__ p1,             // [B][N] scratch
    float* __restrict__ out,            // [B][N]
    float* __restrict__ partial,        // [CHUNKS][B][N]
    unsigned* __restrict__ bar) {       // >=5 zeroed counters
    const int tid = threadIdx.x;
    const int ix  = blockIdx.x & (IPANELS - 1);
    const int c   = blockIdx.x >> 3;               // /IPANELS
    const int i0  = ix * (T1 * 4) + tid * 4;
    const int j0  = c * JC;

    __shared__ __align__(16) float lds_p[JC][B];

    const float* pin[3]  = {preds, p0, p1};
    float* const pout[3] = {p0, p1, out};

#pragma unroll
    for (int it = 0; it < 3; ++it) {
        const float* p = pin[it];
        // ---- stage1: partial products over this block's j-chunk ----
        if (tid < JC * B) {   // 128 threads load 128 floats, transposed
            int j = tid >> 2, b = tid & 3;
            lds_p[j][b] = p[b * N + j0 + j];
        }
        __syncthreads();

        float4 acc[B];
#pragma unroll
        for (int b = 0; b < B; ++b) acc[b] = make_float4(1.f, 1.f, 1.f, 1.f);

        const float* aptr = adj + (size_t)j0 * N + i0;
#pragma unroll 8
        for (int j = 0; j < JC; ++j) {
            float4 a  = *reinterpret_cast<const float4*>(aptr + (size_t)j * N);
            float4 pv = *reinterpret_cast<const float4*>(&lds_p[j][0]);
            const float pb[4] = {pv.x, pv.y, pv.z, pv.w};
#pragma unroll
            for (int b = 0; b < B; ++b) {
                acc[b].x *= fmaf(-a.x, pb[b], 1.f);
                acc[b].y *= fmaf(-a.y, pb[b], 1.f);
                acc[b].z *= fmaf(-a.z, pb[b], 1.f);
                acc[b].w *= fmaf(-a.w, pb[b], 1.f);
            }
        }
#pragma unroll
        for (int b = 0; b < B; ++b)
            *reinterpret_cast<float4*>(partial + ((size_t)(c * B + b)) * N + i0) = acc[b];

        grid_barrier(&bar[2 * it], NBLK);

        // ---- stage2: blocks 0..127 combine chunk partials ----
        if (blockIdx.x < (B * N) / T1) {           // 128 blocks
            int t = blockIdx.x * T1 + tid;         // 0 .. B*N-1
            int b = t >> 12, i = t & (N - 1);
            float prod = 1.f;
#pragma unroll 16
            for (int c2 = 0; c2 < CHUNKS; ++c2)
                prod *= partial[((size_t)(c2 * B + b)) * N + i];
            pout[it][t] = 1.f - prod;
        }
        if (it != 2) grid_barrier(&bar[2 * it + 1], NBLK);
    }
}

// Minimal-scratch fallback (ws confirmed 256 MiB; kept for safety).
__global__ __launch_bounds__(256) void diffusion_full(
    const float* __restrict__ adj, const float* __restrict__ p,
    float* __restrict__ pout) {
    int i = blockIdx.x * 256 + threadIdx.x;
    float acc[B] = {1.f, 1.f, 1.f, 1.f};
    for (int j = 0; j < N; ++j) {
        float a = adj[(size_t)j * N + i];
#pragma unroll
        for (int b = 0; b < B; ++b) acc[b] *= fmaf(-a, p[b * N + j], 1.f);
    }
#pragma unroll
    for (int b = 0; b < B; ++b) pout[b * N + i] = 1.f - acc[b];
}

extern "C" void kernel_launch(void* const* d_in, const int* in_sizes, int n_in,
                              void* d_out, int out_size, void* d_ws, size_t ws_size,
                              hipStream_t stream) {
    const float* preds = (const float*)d_in[0];  // [B][N]
    const float* adj   = (const float*)d_in[1];  // [N][N]
    float* out = (float*)d_out;

    // ws layout (256B-aligned chunks): [bar 256B][partial 8MiB][p0 64KiB][p1 64KiB]
    unsigned* bar  = (unsigned*)d_ws;
    float* partial = (float*)((char*)d_ws + 256);
    float* p0      = partial + (size_t)CHUNKS * B * N;
    float* p1      = p0 + (size_t)B * N;

    const size_t need = 256 + ((size_t)CHUNKS * B * N + 2 * (size_t)B * N) * sizeof(float);

    if (ws_size >= need) {
        hipMemsetAsync(bar, 0, 256, stream);   // capture-legal memset node
        diffusion_fused<<<NBLK, T1, 0, stream>>>(adj, preds, p0, p1, out, partial, bar);
    } else {
        float* q0 = (float*)d_ws;              // B*N floats
        dim3 g(N / 256), b(256);
        diffusion_full<<<g, b, 0, stream>>>(adj, preds, out);
        diffusion_full<<<g, b, 0, stream>>>(adj, out, q0);
        diffusion_full<<<g, b, 0, stream>>>(adj, q0, out);
    }
}

// Round 7
// 160.812 us; speedup vs baseline: 4.7051x; 4.7051x over previous
//
#include <hip/hip_runtime.h>

// DiffusionPropagate: out[b,i] = 1 - prod_j (1 - adj[j,i] * p[b,j]), 3 iters.
// B=4, N=4096. Split 3x(stage1+stage2); j-reduction in CHUNKS partial
// products combined by stage2. R6 fused/grid-barrier experiment: VGPR
// collapsed to 32, fences thrashed L2 -> 201 GB/s. Reverted to split.
// R7: stage1 at 16 waves/CU (T1=256, 1024 blocks) and 4KB-contiguous
// per-row sweep (ITILE=1024, JC=16) to raise in-flight bytes + DRAM page
// locality. R5 baseline: stage1 ~30us = 2.1 TB/s; target 13-16us.

#define N 4096
#define B 4
#define CHUNKS 256
#define JC (N / CHUNKS)      // 16 j per chunk
#define T1 256               // threads per stage1 block (4 waves)
#define ITILE (T1 * 4)       // 1024 output nodes per block (float4 per thread)
#define IPANELS (N / ITILE)  // 4

__global__ __launch_bounds__(T1) void diffusion_stage1(
    const float* __restrict__ adj,     // [N][N] row-major
    const float* __restrict__ p,       // [B][N]
    float* __restrict__ partial) {     // [CHUNKS][B][N]
    // Transposed p-chunk: lds_p[j][b] = p[b][j0+j]; one ds_read_b128 per j
    // broadcasts all 4 batch values (same address across lanes -> no conflict).
    __shared__ __align__(16) float lds_p[JC][B];

    const int tid = threadIdx.x;
    const int i0  = blockIdx.x * ITILE + tid * 4;  // first of 4 output nodes
    const int j0  = blockIdx.y * JC;               // chunk start in source dim

    if (tid < JC * B) {  // 64 threads load 64 floats
        int j = tid >> 2, b = tid & 3;
        lds_p[j][b] = p[b * N + j0 + j];
    }
    __syncthreads();

    float4 acc[B];
#pragma unroll
    for (int b = 0; b < B; ++b) acc[b] = make_float4(1.f, 1.f, 1.f, 1.f);

    const float* aptr = adj + (size_t)j0 * N + i0;

#pragma unroll 8
    for (int j = 0; j < JC; ++j) {
        float4 a  = *reinterpret_cast<const float4*>(aptr + (size_t)j * N);
        float4 pv = *reinterpret_cast<const float4*>(&lds_p[j][0]);
        const float pb[4] = {pv.x, pv.y, pv.z, pv.w};
#pragma unroll
        for (int b = 0; b < B; ++b) {
            acc[b].x *= fmaf(-a.x, pb[b], 1.f);
            acc[b].y *= fmaf(-a.y, pb[b], 1.f);
            acc[b].z *= fmaf(-a.z, pb[b], 1.f);
            acc[b].w *= fmaf(-a.w, pb[b], 1.f);
        }
    }

    const int c = blockIdx.y;
#pragma unroll
    for (int b = 0; b < B; ++b) {
        *reinterpret_cast<float4*>(partial + ((size_t)(c * B + b)) * N + i0) = acc[b];
    }
}

__global__ __launch_bounds__(256) void diffusion_stage2(
    const float* __restrict__ partial,  // [CHUNKS][B][N]
    float* __restrict__ pout) {         // [B][N]
    int t = blockIdx.x * 256 + threadIdx.x;  // 0 .. B*N-1
    int b = t >> 12;        // /N
    int i = t & (N - 1);    // %N
    float prod = 1.f;
#pragma unroll 16
    for (int c = 0; c < CHUNKS; ++c)
        prod *= partial[((size_t)(c * B + b)) * N + i];
    pout[t] = 1.f - prod;
}

// Minimal-scratch fallback (ws confirmed 256 MiB; kept for safety).
__global__ __launch_bounds__(256) void diffusion_full(
    const float* __restrict__ adj, const float* __restrict__ p,
    float* __restrict__ pout) {
    int i = blockIdx.x * 256 + threadIdx.x;
    float acc[B] = {1.f, 1.f, 1.f, 1.f};
    for (int j = 0; j < N; ++j) {
        float a = adj[(size_t)j * N + i];
#pragma unroll
        for (int b = 0; b < B; ++b) acc[b] *= fmaf(-a, p[b * N + j], 1.f);
    }
#pragma unroll
    for (int b = 0; b < B; ++b) pout[b * N + i] = 1.f - acc[b];
}

extern "C" void kernel_launch(void* const* d_in, const int* in_sizes, int n_in,
                              void* d_out, int out_size, void* d_ws, size_t ws_size,
                              hipStream_t stream) {
    const float* preds = (const float*)d_in[0];  // [B][N]
    const float* adj   = (const float*)d_in[1];  // [N][N]
    // d_in[2] = niter (always 3)
    float* out = (float*)d_out;

    float* p0      = (float*)d_ws;               // B*N floats (ping-pong scratch)
    float* partial = p0 + (size_t)B * N;         // CHUNKS*B*N floats (16 MiB)

    const size_t need = ((size_t)B * N + (size_t)CHUNKS * B * N) * sizeof(float);

    if (ws_size >= need) {
        dim3 g1(IPANELS, CHUNKS), b1(T1);        // 4 x 256 = 1024 blocks, 4 waves each
        dim3 g2((B * N) / 256), b2(256);         // 64 blocks
        // iter 1: preds -> out ; iter 2: out -> p0 ; iter 3: p0 -> out
        diffusion_stage1<<<g1, b1, 0, stream>>>(adj, preds, partial);
        diffusion_stage2<<<g2, b2, 0, stream>>>(partial, out);
        diffusion_stage1<<<g1, b1, 0, stream>>>(adj, out, partial);
        diffusion_stage2<<<g2, b2, 0, stream>>>(partial, p0);
        diffusion_stage1<<<g1, b1, 0, stream>>>(adj, p0, partial);
        diffusion_stage2<<<g2, b2, 0, stream>>>(partial, out);
    } else {
        dim3 g(N / 256), b(256);
        diffusion_full<<<g, b, 0, stream>>>(adj, preds, out);
        diffusion_full<<<g, b, 0, stream>>>(adj, out, p0);
        diffusion_full<<<g, b, 0, stream>>>(adj, p0, out);
    }
}